// Round 2
// baseline (769.910 us; speedup 1.0000x reference)
//
#include <hip/hip_runtime.h>

// EnhancedEdgeLayer: fused edge-bank -> conv1(9->32,3x3)+ReLU -> conv2(32->16,3x3)+ReLU -> +1x1 residual
// x [8,1,512,512] f32 -> out [8,16,512,512] f32
//
// One block = one 16x16 output tile for one batch image, all 16 output channels.
// Border semantics (matches reference exactly):
//   - grads: conv(x, bank, pad=2) -> x zero-padded (xs tile zero outside image)
//   - conv1 input: feats zero-padded by 1 -> fs zero outside image
//   - conv2 input: h zero-padded by 1 -> hs MUST be 0 outside image (not relu(conv1) there!)

#define TO 16   // output tile
#define XT 24   // x tile side
#define FT 20   // feats tile side (logical)
#define FP 21   // feats row stride (padded, conflict-free)
#define HT 18   // h tile side

__global__ __launch_bounds__(256) void fused_edge_kernel(
    const float* __restrict__ x,  const float* __restrict__ w1, const float* __restrict__ b1,
    const float* __restrict__ w2, const float* __restrict__ b2,
    const float* __restrict__ wr, const float* __restrict__ br,
    float* __restrict__ out)
{
    __shared__ float xs[XT * XT];
    __shared__ float fs[9 * FT * FP];
    __shared__ float hs[8 * HT * HT];
    __shared__ float w1s[32 * 9 * 9];    // [oc][ch][tap] == global flat layout
    __shared__ float w2s[32 * 9 * 16];   // [(ic*9+tap)*16 + oc]
    __shared__ float b1s[32], b2s[16], wrs[16], brs[16];

    const int tid = threadIdx.x;
    const int bx = blockIdx.x * TO;
    const int by = blockIdx.y * TO;
    const int b  = blockIdx.z;

    // ---- stage weights ----
    for (int i = tid; i < 32 * 9 * 9; i += 256) w1s[i] = w1[i];
    for (int i = tid; i < 16 * 32 * 9; i += 256) {
        int ic  = i / (9 * 16);
        int r   = i % (9 * 16);
        int tap = r / 16;
        int oc  = r & 15;
        w2s[i] = w2[(oc * 32 + ic) * 9 + tap];
    }
    if (tid < 32) b1s[tid] = b1[tid];
    if (tid < 16) { b2s[tid] = b2[tid]; wrs[tid] = wr[tid]; brs[tid] = br[tid]; }

    // ---- x tile (zero-padded) ----
    for (int i = tid; i < XT * XT; i += 256) {
        int r = i / XT, c = i % XT;
        int gy = by - 4 + r, gx = bx - 4 + c;
        float v = 0.f;
        if (gy >= 0 && gy < 512 && gx >= 0 && gx < 512)
            v = x[(b * 512 + gy) * 512 + gx];
        xs[i] = v;
    }
    __syncthreads();

    // ---- feats: 8 stencils + identity, zero outside image (= conv1's zero pad) ----
    for (int i = tid; i < 9 * FT * FT; i += 256) {
        int ch = i / (FT * FT);
        int p  = i % (FT * FT);
        int r  = p / FT, c = p % FT;
        int gy = by - 2 + r, gx = bx - 2 + c;
        float v = 0.f;
        if (gy >= 0 && gy < 512 && gx >= 0 && gx < 512) {
            const float* xc = &xs[r * XT + c];
#define X(a, bb) xc[(a) * XT + (bb)]
            switch (ch) {
            case 0: v = -X(1,1)+X(1,3) - 2.f*X(2,1)+2.f*X(2,3) - X(3,1)+X(3,3); break;           // sobel_x
            case 1: v = -X(1,1)-2.f*X(1,2)-X(1,3) + X(3,1)+2.f*X(3,2)+X(3,3); break;             // sobel_y
            case 2: v =  X(1,2)+2.f*X(1,3) - X(2,1)+X(2,3) - 2.f*X(3,1)-X(3,2); break;           // diag1
            case 3: v = -2.f*X(1,1)-X(1,2) - X(2,1)+X(2,3) + X(3,2)+2.f*X(3,3); break;           // diag2
            case 4: v =  X(1,2)+X(2,1)-4.f*X(2,2)+X(2,3)+X(3,2); break;                           // laplacian
            case 5: v = -1.f*X(0,0)-2.f*X(0,1)+2.f*X(0,3)+1.f*X(0,4)
                        -2.f*X(1,0)-3.f*X(1,1)+3.f*X(1,3)+2.f*X(1,4)
                        -3.f*X(2,0)-4.f*X(2,1)+4.f*X(2,3)+3.f*X(2,4)
                        -2.f*X(3,0)-3.f*X(3,1)+3.f*X(3,3)+2.f*X(3,4)
                        -1.f*X(4,0)-2.f*X(4,1)+2.f*X(4,3)+1.f*X(4,4); break;                      // gradient5x5
            case 6: v = -3.f*X(1,1)+3.f*X(1,3)-10.f*X(2,1)+10.f*X(2,3)-3.f*X(3,1)+3.f*X(3,3); break; // scharr_x
            case 7: v = -3.f*X(1,1)-10.f*X(1,2)-3.f*X(1,3)+3.f*X(3,1)+10.f*X(3,2)+3.f*X(3,3); break; // scharr_y
            default: v = X(2,2); break;                                                           // identity (x)
            }
#undef X
        }
        fs[ch * FT * FP + r * FP + c] = v;
    }

    // ---- conv2 accumulators: thread = (oc, py), 16 px per thread ----
    const int py = tid & 15;
    const int oc = tid >> 4;
    float acc[TO];
#pragma unroll
    for (int i = 0; i < TO; ++i) acc[i] = 0.f;

    for (int chunk = 0; chunk < 4; ++chunk) {
        __syncthreads();  // feats ready (iter 0) / previous conv2 done reading hs
        if (tid < 144) {
            const int ocl = tid / 18;
            const int row = tid % 18;
            const int hoc = chunk * 8 + ocl;
            const int hy  = by - 1 + row;
            const bool rowok = (hy >= 0 && hy < 512);
            float a[HT];
            const float bias = b1s[hoc];
#pragma unroll
            for (int i = 0; i < HT; ++i) a[i] = bias;
            for (int ch = 0; ch < 9; ++ch) {
#pragma unroll
                for (int dy = 0; dy < 3; ++dy) {
                    const float* frow = &fs[ch * FT * FP + (row + dy) * FP];
                    float f[FT];
#pragma unroll
                    for (int j = 0; j < FT; ++j) f[j] = frow[j];
#pragma unroll
                    for (int dx = 0; dx < 3; ++dx) {
                        const float w = w1s[(hoc * 9 + ch) * 9 + dy * 3 + dx];
#pragma unroll
                        for (int col = 0; col < HT; ++col)
                            a[col] = fmaf(f[col + dx], w, a[col]);
                    }
                }
            }
            float* hrow = &hs[ocl * HT * HT + row * HT];
#pragma unroll
            for (int col = 0; col < HT; ++col) {
                const int hx = bx - 1 + col;
                const bool ok = rowok && (hx >= 0) && (hx < 512);
                hrow[col] = ok ? fmaxf(a[col], 0.f) : 0.f;   // h outside image == conv2 zero pad
            }
        }
        __syncthreads();  // hs ready
        for (int icl = 0; icl < 8; ++icl) {
            const int ic = chunk * 8 + icl;
            float w2r[9];
#pragma unroll
            for (int t = 0; t < 9; ++t) w2r[t] = w2s[(ic * 9 + t) * 16 + oc];
#pragma unroll
            for (int dy = 0; dy < 3; ++dy) {
                const float* hrow = &hs[icl * HT * HT + (py + dy) * HT];
                float hv[HT];
#pragma unroll
                for (int j = 0; j < HT; ++j) hv[j] = hrow[j];
#pragma unroll
                for (int dx = 0; dx < 3; ++dx) {
                    const float w = w2r[dy * 3 + dx];
#pragma unroll
                    for (int px = 0; px < TO; ++px)
                        acc[px] = fmaf(hv[px + dx], w, acc[px]);
                }
            }
        }
    }

    // ---- epilogue: relu(conv2 + b2) + residual ----
    const float bias2 = b2s[oc], wrv = wrs[oc], brv = brs[oc];
    float ov[TO];
#pragma unroll
    for (int px = 0; px < TO; ++px) {
        const float xv = xs[(py + 4) * XT + (px + 4)];
        ov[px] = fmaxf(acc[px] + bias2, 0.f) + wrv * xv + brv;
    }
    float* orow = &out[(((size_t)b * 16 + oc) * 512 + (by + py)) * 512 + bx];
#pragma unroll
    for (int q = 0; q < 4; ++q) {
        float4 v4 = make_float4(ov[4*q], ov[4*q+1], ov[4*q+2], ov[4*q+3]);
        *reinterpret_cast<float4*>(&orow[4 * q]) = v4;
    }
}

extern "C" void kernel_launch(void* const* d_in, const int* in_sizes, int n_in,
                              void* d_out, int out_size, void* d_ws, size_t ws_size,
                              hipStream_t stream) {
    const float* x  = (const float*)d_in[0];
    const float* w1 = (const float*)d_in[1];
    const float* b1 = (const float*)d_in[2];
    const float* w2 = (const float*)d_in[3];
    const float* b2 = (const float*)d_in[4];
    const float* wr = (const float*)d_in[5];
    const float* br = (const float*)d_in[6];
    float* out = (float*)d_out;

    dim3 grid(512 / TO, 512 / TO, 8);
    dim3 block(256);
    hipLaunchKernelGGL(fused_edge_kernel, grid, block, 0, stream,
                       x, w1, b1, w2, b2, wr, br, out);
}

// Round 3
// 351.946 us; speedup vs baseline: 2.1876x; 2.1876x over previous
//
#include <hip/hip_runtime.h>

// EnhancedEdgeLayer via bf16 MFMA (gfx950 mfma_f32_16x16x32_bf16).
// x [8,1,512,512] f32 -> out [8,16,512,512] f32
// Block = 16x16 output tile, 256 threads (4 waves), grid 32x32x8.
//
// Phases:
//  P0 xs[24x24] fp32 x-tile (zero-padded) -> LDS
//  P1 weight A-fragments global->registers (L1-cached); per-lane gather tables
//  P2 feats: 8 stencils + identity -> fs bf16 [400 px][24 ch-slots] (slots 9..23 zero)
//     K1-order: k = (dy*3+dx)*16 + ch  (9 tap-groups x 16 ch-slots = 144, pad->160)
//  P3 conv1: 21 n-tiles x 5 K-steps x 2 M-tiles MFMA -> hs bf16 [324 px][40 ic-slots]
//     (h outside image written as 0 = conv2's zero pad; bias+relu in fp32 epilogue)
//  P4 conv2: 16 n-tiles (=output rows) x 9 K-steps MFMA; K2-order: k = tap*32 + ic
//     epilogue fp32: +b2, relu, + wr*x + br, coalesced stores.
//
// K-slot assignment is the SAME bijection for A and B fragments, so correctness
// is independent of the hardware's internal k interleave. Lane mapping used:
// A row = lane&15, B col = lane&15, k-group = lane>>4 (8 elems each); C/D per m89.

typedef __attribute__((ext_vector_type(8))) short bf16x8;
typedef __attribute__((ext_vector_type(4))) float f32x4;

#define FS_SLOT 24   // shorts per feats px (48B stride)
#define HS_SLOT 40   // shorts per h px (80B stride)

__device__ __forceinline__ unsigned short f2bf(float f) {
    union { float f; unsigned u; } v; v.f = f;
    unsigned u = v.u + 0x7fffu + ((v.u >> 16) & 1u);   // RNE
    return (unsigned short)(u >> 16);
}
__device__ __forceinline__ unsigned pk(float lo, float hi) {
    return (unsigned)f2bf(lo) | ((unsigned)f2bf(hi) << 16);
}

__global__ __launch_bounds__(256, 3) void fused_edge_mfma(
    const float* __restrict__ x,  const float* __restrict__ w1, const float* __restrict__ b1,
    const float* __restrict__ w2, const float* __restrict__ b2,
    const float* __restrict__ wr, const float* __restrict__ br,
    float* __restrict__ out)
{
    __shared__ short fs[400 * FS_SLOT];   // 19200 B
    __shared__ short hs[324 * HS_SLOT];   // 25920 B
    __shared__ float xs[24 * 24];         //  2304 B

    const int tid  = threadIdx.x;
    const int lane = tid & 63;
    const int wave = tid >> 6;
    const int n    = lane & 15;
    const int lg   = lane >> 4;
    const int bx = blockIdx.x * 16, by = blockIdx.y * 16, b = blockIdx.z;

    // ---- P0: x tile (zero-padded) ----
    for (int i = tid; i < 576; i += 256) {
        int r = i / 24, c = i % 24;
        int gy = by - 4 + r, gx = bx - 4 + c;
        float v = 0.f;
        if (gy >= 0 && gy < 512 && gx >= 0 && gx < 512) v = x[(b * 512 + gy) * 512 + gx];
        xs[i] = v;
    }

    // ---- P1: weight fragments -> registers (global reads, L1-cached) ----
    bf16x8 a1[2][5];
#pragma unroll
    for (int mt = 0; mt < 2; ++mt)
#pragma unroll
        for (int ks = 0; ks < 5; ++ks)
#pragma unroll
            for (int i = 0; i < 8; ++i) {
                int k = 32 * ks + 8 * lg + i;
                int g = k >> 4, ch = k & 15;         // tap group, ch-slot
                float w = (g < 9 && ch < 9) ? w1[(mt * 16 + n) * 81 + ch * 9 + g] : 0.f;
                a1[mt][ks][i] = (short)f2bf(w);
            }
    bf16x8 a2[9];
#pragma unroll
    for (int ks = 0; ks < 9; ++ks)
#pragma unroll
        for (int i = 0; i < 8; ++i) {
            int ic = 8 * lg + i;
            a2[ks][i] = (short)f2bf(w2[n * 288 + ic * 9 + ks]);
        }
    float b1v[2][4], b2v[4], wrv[4], brv[4];
#pragma unroll
    for (int mt = 0; mt < 2; ++mt)
#pragma unroll
        for (int r = 0; r < 4; ++r) b1v[mt][r] = b1[mt * 16 + lg * 4 + r];
#pragma unroll
    for (int r = 0; r < 4; ++r) {
        b2v[r] = b2[lg * 4 + r]; wrv[r] = wr[lg * 4 + r]; brv[r] = br[lg * 4 + r];
    }
    int boff[5];  // per-lane conv1 B-gather offsets (short units)
#pragma unroll
    for (int ks = 0; ks < 5; ++ks) {
        int g = 2 * ks + (lg >> 1); if (g > 8) g = 8;   // g==9 slots have A==0
        int dy = g / 3, dx = g - 3 * dy;
        boff[ks] = (dy * 20 + dx) * FS_SLOT + (lg & 1) * 8;
    }

    __syncthreads();

    // ---- P2: feats -> fs bf16 [px][24 slots] ----
    for (int p = tid; p < 400; p += 256) {
        int r = p / 20, c = p % 20;
        int fy = by + r - 2, fx = bx + c - 2;
        float m = (fy >= 0 && fy < 512 && fx >= 0 && fx < 512) ? 1.f : 0.f;
        const float* wp = &xs[r * 24 + c];
        float t[5][5];
#pragma unroll
        for (int a = 0; a < 5; ++a)
#pragma unroll
            for (int bb = 0; bb < 5; ++bb) t[a][bb] = wp[a * 24 + bb];
        float f0 = -t[1][1]+t[1][3] - 2.f*t[2][1]+2.f*t[2][3] - t[3][1]+t[3][3];
        float f1 = -t[1][1]-2.f*t[1][2]-t[1][3] + t[3][1]+2.f*t[3][2]+t[3][3];
        float f2 =  t[1][2]+2.f*t[1][3] - t[2][1]+t[2][3] - 2.f*t[3][1]-t[3][2];
        float f3 = -2.f*t[1][1]-t[1][2] - t[2][1]+t[2][3] + t[3][2]+2.f*t[3][3];
        float f4 =  t[1][2]+t[2][1]-4.f*t[2][2]+t[2][3]+t[3][2];
        float f5 = -1.f*t[0][0]-2.f*t[0][1]+2.f*t[0][3]+1.f*t[0][4]
                   -2.f*t[1][0]-3.f*t[1][1]+3.f*t[1][3]+2.f*t[1][4]
                   -3.f*t[2][0]-4.f*t[2][1]+4.f*t[2][3]+3.f*t[2][4]
                   -2.f*t[3][0]-3.f*t[3][1]+3.f*t[3][3]+2.f*t[3][4]
                   -1.f*t[4][0]-2.f*t[4][1]+2.f*t[4][3]+1.f*t[4][4];
        float f6 = -3.f*t[1][1]+3.f*t[1][3]-10.f*t[2][1]+10.f*t[2][3]-3.f*t[3][1]+3.f*t[3][3];
        float f7 = -3.f*t[1][1]-10.f*t[1][2]-3.f*t[1][3]+3.f*t[3][1]+10.f*t[3][2]+3.f*t[3][3];
        float f8 =  t[2][2];
        f0*=m; f1*=m; f2*=m; f3*=m; f4*=m; f5*=m; f6*=m; f7*=m; f8*=m;
        uint4 A; A.x = pk(f0,f1); A.y = pk(f2,f3); A.z = pk(f4,f5); A.w = pk(f6,f7);
        uint4 B; B.x = pk(f8,0.f); B.y = 0u; B.z = 0u; B.w = 0u;
        uint4 Z; Z.x = 0u; Z.y = 0u; Z.z = 0u; Z.w = 0u;
        *reinterpret_cast<uint4*>(&fs[p * FS_SLOT])      = A;
        *reinterpret_cast<uint4*>(&fs[p * FS_SLOT + 8])  = B;
        *reinterpret_cast<uint4*>(&fs[p * FS_SLOT + 16]) = Z;
    }
    __syncthreads();

    // ---- P3: conv1 MFMA -> hs ----
    for (int tIdx = wave; tIdx < 21; tIdx += 4) {
        int p  = tIdx * 16 + n;
        int pc = p < 323 ? p : 323;               // clamp for safe addresses
        int r1 = pc / 18, c1 = pc - r1 * 18;
        int base = (r1 * 20 + c1) * FS_SLOT;
        f32x4 acc0 = {0.f,0.f,0.f,0.f}, acc1 = {0.f,0.f,0.f,0.f};
#pragma unroll
        for (int ks = 0; ks < 5; ++ks) {
            bf16x8 bf = *reinterpret_cast<const bf16x8*>(&fs[base + boff[ks]]);
            acc0 = __builtin_amdgcn_mfma_f32_16x16x32_bf16(a1[0][ks], bf, acc0, 0, 0, 0);
            acc1 = __builtin_amdgcn_mfma_f32_16x16x32_bf16(a1[1][ks], bf, acc1, 0, 0, 0);
        }
        if (p < 324) {
            int hy = by - 1 + r1, hx = bx - 1 + c1;
            float m = (hy >= 0 && hy < 512 && hx >= 0 && hx < 512) ? 1.f : 0.f;
            float h0 = fmaxf(acc0[0] + b1v[0][0], 0.f) * m;
            float h1 = fmaxf(acc0[1] + b1v[0][1], 0.f) * m;
            float h2 = fmaxf(acc0[2] + b1v[0][2], 0.f) * m;
            float h3 = fmaxf(acc0[3] + b1v[0][3], 0.f) * m;
            uint2 W0; W0.x = pk(h0, h1); W0.y = pk(h2, h3);
            *reinterpret_cast<uint2*>(&hs[p * HS_SLOT + lg * 4]) = W0;
            float g0 = fmaxf(acc1[0] + b1v[1][0], 0.f) * m;
            float g1 = fmaxf(acc1[1] + b1v[1][1], 0.f) * m;
            float g2 = fmaxf(acc1[2] + b1v[1][2], 0.f) * m;
            float g3 = fmaxf(acc1[3] + b1v[1][3], 0.f) * m;
            uint2 W1; W1.x = pk(g0, g1); W1.y = pk(g2, g3);
            *reinterpret_cast<uint2*>(&hs[p * HS_SLOT + 16 + lg * 4]) = W1;
        }
    }
    __syncthreads();

    // ---- P4: conv2 MFMA + epilogue ----
    const int hlane = n * HS_SLOT + lg * 8;
#pragma unroll
    for (int j = 0; j < 4; ++j) {
        int oy = wave + 4 * j;
        f32x4 acc = {0.f,0.f,0.f,0.f};
#pragma unroll
        for (int ks = 0; ks < 9; ++ks) {
            const int dy = ks / 3, dx = ks - 3 * (ks / 3);
            bf16x8 hf = *reinterpret_cast<const bf16x8*>(
                &hs[((oy + dy) * 18 + dx) * HS_SLOT + hlane]);
            acc = __builtin_amdgcn_mfma_f32_16x16x32_bf16(a2[ks], hf, acc, 0, 0, 0);
        }
        float xv = xs[(oy + 4) * 24 + n + 4];
#pragma unroll
        for (int r = 0; r < 4; ++r) {
            float o = fmaxf(acc[r] + b2v[r], 0.f) + wrv[r] * xv + brv[r];
            out[(((size_t)b * 16 + lg * 4 + r) * 512 + (by + oy)) * 512 + (bx + n)] = o;
        }
    }
}

extern "C" void kernel_launch(void* const* d_in, const int* in_sizes, int n_in,
                              void* d_out, int out_size, void* d_ws, size_t ws_size,
                              hipStream_t stream) {
    const float* x  = (const float*)d_in[0];
    const float* w1 = (const float*)d_in[1];
    const float* b1 = (const float*)d_in[2];
    const float* w2 = (const float*)d_in[3];
    const float* b2 = (const float*)d_in[4];
    const float* wr = (const float*)d_in[5];
    const float* br = (const float*)d_in[6];
    float* out = (float*)d_out;

    dim3 grid(32, 32, 8);
    dim3 block(256);
    hipLaunchKernelGGL(fused_edge_mfma, grid, block, 0, stream,
                       x, w1, b1, w2, b2, wr, br, out);
}

// Round 4
// 121.965 us; speedup vs baseline: 6.3126x; 2.8856x over previous
//
#include <hip/hip_runtime.h>

// EnhancedEdgeLayer via bf16 MFMA (gfx950 mfma_f32_16x16x32_bf16).
// x [8,1,512,512] f32 -> out [8,16,512,512] f32
// Block = 16x16 output tile, 256 threads (4 waves), grid 32x32x8.
//
// R4 changes vs R3:
//  - setup kernel pre-swizzles weight fragments into d_ws (per-lane bf16x8 layout):
//    main-kernel P1 = ~24 coalesced 16B loads instead of ~150 scattered loads + f2bf.
//  - nontemporal output stores: avoid TCC write-allocate RMW (64B segments into
//    128B lines caused ~256 MiB of bogus FETCH).
//  - LDS 47.6->40.3 KB (FS_SLOT 24->20, HS_SLOT 40->34) -> 4 blocks/CU.

typedef __attribute__((ext_vector_type(8))) short bf16x8;
typedef __attribute__((ext_vector_type(4))) float f32x4;

#define FS_SLOT 20   // shorts per feats px (40B stride; slots 0..15 used)
#define HS_SLOT 34   // shorts per h px (68B stride; slots 0..31 used)

// ws layout (shorts): A1 [2][5][64][8] @0 (5120), A2 [9][64][8] @5120 (4608)
// floats @ byte 19456: per-lane 20: b1v[2][4], b2v[4], wrv[4], brv[4]
#define WS_A2 5120
#define WS_FLOAT_OFF 4864   // in floats
#define WS_BYTES 24576

__device__ __forceinline__ unsigned short f2bf(float f) {
    union { float f; unsigned u; } v; v.f = f;
    unsigned u = v.u + 0x7fffu + ((v.u >> 16) & 1u);   // RNE
    return (unsigned short)(u >> 16);
}
__device__ __forceinline__ unsigned pk(float lo, float hi) {
    return (unsigned)f2bf(lo) | ((unsigned)f2bf(hi) << 16);
}

__global__ __launch_bounds__(64) void setup_frags(
    const float* __restrict__ w1, const float* __restrict__ b1,
    const float* __restrict__ w2, const float* __restrict__ b2,
    const float* __restrict__ wr, const float* __restrict__ br,
    short* __restrict__ ws)
{
    const int lane = threadIdx.x;
    const int n = lane & 15, lg = lane >> 4;
    for (int mt = 0; mt < 2; ++mt)
        for (int ks = 0; ks < 5; ++ks)
            for (int i = 0; i < 8; ++i) {
                int k = 32 * ks + 8 * lg + i;
                int g = k >> 4, ch = k & 15;
                float w = (g < 9 && ch < 9) ? w1[(mt * 16 + n) * 81 + ch * 9 + g] : 0.f;
                ws[((mt * 5 + ks) * 64 + lane) * 8 + i] = (short)f2bf(w);
            }
    for (int ks = 0; ks < 9; ++ks)
        for (int i = 0; i < 8; ++i) {
            int ic = 8 * lg + i;
            ws[WS_A2 + (ks * 64 + lane) * 8 + i] = (short)f2bf(w2[n * 288 + ic * 9 + ks]);
        }
    float* wf = (float*)ws + WS_FLOAT_OFF + lane * 20;
    for (int r = 0; r < 4; ++r) {
        wf[r]      = b1[lg * 4 + r];
        wf[4 + r]  = b1[16 + lg * 4 + r];
        wf[8 + r]  = b2[lg * 4 + r];
        wf[12 + r] = wr[lg * 4 + r];
        wf[16 + r] = br[lg * 4 + r];
    }
}

template<bool USE_WS>
__global__ __launch_bounds__(256, 4) void fused_edge_mfma(
    const float* __restrict__ x,  const float* __restrict__ w1, const float* __restrict__ b1,
    const float* __restrict__ w2, const float* __restrict__ b2,
    const float* __restrict__ wr, const float* __restrict__ br,
    const short* __restrict__ ws, float* __restrict__ out)
{
    __shared__ short fs[400 * FS_SLOT];   // 16000 B
    __shared__ short hs[324 * HS_SLOT];   // 22032 B
    __shared__ float xs[24 * 24];         //  2304 B

    const int tid  = threadIdx.x;
    const int lane = tid & 63;
    const int wave = tid >> 6;
    const int n    = lane & 15;
    const int lg   = lane >> 4;
    const int bx = blockIdx.x * 16, by = blockIdx.y * 16, b = blockIdx.z;

    // ---- P0: x tile (zero-padded) ----
    for (int i = tid; i < 576; i += 256) {
        int r = i / 24, c = i % 24;
        int gy = by - 4 + r, gx = bx - 4 + c;
        float v = 0.f;
        if (gy >= 0 && gy < 512 && gx >= 0 && gx < 512) v = x[(b * 512 + gy) * 512 + gx];
        xs[i] = v;
    }

    // ---- P1: weight fragments -> registers ----
    bf16x8 a1[2][5];
    bf16x8 a2[9];
    float b1v[2][4], b2v[4], wrv[4], brv[4];
    if (USE_WS) {
#pragma unroll
        for (int mt = 0; mt < 2; ++mt)
#pragma unroll
            for (int ks = 0; ks < 5; ++ks)
                a1[mt][ks] = *reinterpret_cast<const bf16x8*>(&ws[((mt * 5 + ks) * 64 + lane) * 8]);
#pragma unroll
        for (int ks = 0; ks < 9; ++ks)
            a2[ks] = *reinterpret_cast<const bf16x8*>(&ws[WS_A2 + (ks * 64 + lane) * 8]);
        const float* wf = (const float*)ws + WS_FLOAT_OFF + lane * 20;
        f32x4 t0 = *reinterpret_cast<const f32x4*>(wf);
        f32x4 t1 = *reinterpret_cast<const f32x4*>(wf + 4);
        f32x4 t2 = *reinterpret_cast<const f32x4*>(wf + 8);
        f32x4 t3 = *reinterpret_cast<const f32x4*>(wf + 12);
        f32x4 t4 = *reinterpret_cast<const f32x4*>(wf + 16);
#pragma unroll
        for (int r = 0; r < 4; ++r) {
            b1v[0][r] = t0[r]; b1v[1][r] = t1[r];
            b2v[r] = t2[r]; wrv[r] = t3[r]; brv[r] = t4[r];
        }
    } else {
#pragma unroll
        for (int mt = 0; mt < 2; ++mt)
#pragma unroll
            for (int ks = 0; ks < 5; ++ks)
#pragma unroll
                for (int i = 0; i < 8; ++i) {
                    int k = 32 * ks + 8 * lg + i;
                    int g = k >> 4, ch = k & 15;
                    float w = (g < 9 && ch < 9) ? w1[(mt * 16 + n) * 81 + ch * 9 + g] : 0.f;
                    a1[mt][ks][i] = (short)f2bf(w);
                }
#pragma unroll
        for (int ks = 0; ks < 9; ++ks)
#pragma unroll
            for (int i = 0; i < 8; ++i) {
                int ic = 8 * lg + i;
                a2[ks][i] = (short)f2bf(w2[n * 288 + ic * 9 + ks]);
            }
#pragma unroll
        for (int mt = 0; mt < 2; ++mt)
#pragma unroll
            for (int r = 0; r < 4; ++r) b1v[mt][r] = b1[mt * 16 + lg * 4 + r];
#pragma unroll
        for (int r = 0; r < 4; ++r) {
            b2v[r] = b2[lg * 4 + r]; wrv[r] = wr[lg * 4 + r]; brv[r] = br[lg * 4 + r];
        }
    }
    int boff[5];  // per-lane conv1 B-gather offsets (short units)
#pragma unroll
    for (int ks = 0; ks < 5; ++ks) {
        int g = 2 * ks + (lg >> 1); if (g > 8) g = 8;   // g==9 slots have A==0
        int dy = g / 3, dx = g - 3 * dy;
        boff[ks] = (dy * 20 + dx) * FS_SLOT + (lg & 1) * 8;
    }

    __syncthreads();

    // ---- P2: feats -> fs bf16 [px][20 slots] (slots 0..8 stencils+x, 9..15 zero) ----
    for (int p = tid; p < 400; p += 256) {
        int r = p / 20, c = p % 20;
        int fy = by + r - 2, fx = bx + c - 2;
        float m = (fy >= 0 && fy < 512 && fx >= 0 && fx < 512) ? 1.f : 0.f;
        const float* wp = &xs[r * 24 + c];
        float t[5][5];
#pragma unroll
        for (int a = 0; a < 5; ++a)
#pragma unroll
            for (int bb = 0; bb < 5; ++bb) t[a][bb] = wp[a * 24 + bb];
        float f0 = -t[1][1]+t[1][3] - 2.f*t[2][1]+2.f*t[2][3] - t[3][1]+t[3][3];
        float f1 = -t[1][1]-2.f*t[1][2]-t[1][3] + t[3][1]+2.f*t[3][2]+t[3][3];
        float f2 =  t[1][2]+2.f*t[1][3] - t[2][1]+t[2][3] - 2.f*t[3][1]-t[3][2];
        float f3 = -2.f*t[1][1]-t[1][2] - t[2][1]+t[2][3] + t[3][2]+2.f*t[3][3];
        float f4 =  t[1][2]+t[2][1]-4.f*t[2][2]+t[2][3]+t[3][2];
        float f5 = -1.f*t[0][0]-2.f*t[0][1]+2.f*t[0][3]+1.f*t[0][4]
                   -2.f*t[1][0]-3.f*t[1][1]+3.f*t[1][3]+2.f*t[1][4]
                   -3.f*t[2][0]-4.f*t[2][1]+4.f*t[2][3]+3.f*t[2][4]
                   -2.f*t[3][0]-3.f*t[3][1]+3.f*t[3][3]+2.f*t[3][4]
                   -1.f*t[4][0]-2.f*t[4][1]+2.f*t[4][3]+1.f*t[4][4];
        float f6 = -3.f*t[1][1]+3.f*t[1][3]-10.f*t[2][1]+10.f*t[2][3]-3.f*t[3][1]+3.f*t[3][3];
        float f7 = -3.f*t[1][1]-10.f*t[1][2]-3.f*t[1][3]+3.f*t[3][1]+10.f*t[3][2]+3.f*t[3][3];
        float f8 =  t[2][2];
        f0*=m; f1*=m; f2*=m; f3*=m; f4*=m; f5*=m; f6*=m; f7*=m; f8*=m;
        uint4 A; A.x = pk(f0,f1); A.y = pk(f2,f3); A.z = pk(f4,f5); A.w = pk(f6,f7);
        uint4 B; B.x = pk(f8,0.f); B.y = 0u; B.z = 0u; B.w = 0u;
        *reinterpret_cast<uint4*>(&fs[p * FS_SLOT])     = A;
        *reinterpret_cast<uint4*>(&fs[p * FS_SLOT + 8]) = B;
    }
    __syncthreads();

    // ---- P3: conv1 MFMA -> hs ----
    for (int tIdx = wave; tIdx < 21; tIdx += 4) {
        int p  = tIdx * 16 + n;
        int pc = p < 323 ? p : 323;               // clamp for safe addresses
        int r1 = pc / 18, c1 = pc - r1 * 18;
        int base = (r1 * 20 + c1) * FS_SLOT;
        f32x4 acc0 = {0.f,0.f,0.f,0.f}, acc1 = {0.f,0.f,0.f,0.f};
#pragma unroll
        for (int ks = 0; ks < 5; ++ks) {
            bf16x8 bf = *reinterpret_cast<const bf16x8*>(&fs[base + boff[ks]]);
            acc0 = __builtin_amdgcn_mfma_f32_16x16x32_bf16(a1[0][ks], bf, acc0, 0, 0, 0);
            acc1 = __builtin_amdgcn_mfma_f32_16x16x32_bf16(a1[1][ks], bf, acc1, 0, 0, 0);
        }
        if (p < 324) {
            int hy = by - 1 + r1, hx = bx - 1 + c1;
            float m = (hy >= 0 && hy < 512 && hx >= 0 && hx < 512) ? 1.f : 0.f;
            float h0 = fmaxf(acc0[0] + b1v[0][0], 0.f) * m;
            float h1 = fmaxf(acc0[1] + b1v[0][1], 0.f) * m;
            float h2 = fmaxf(acc0[2] + b1v[0][2], 0.f) * m;
            float h3 = fmaxf(acc0[3] + b1v[0][3], 0.f) * m;
            uint2 W0; W0.x = pk(h0, h1); W0.y = pk(h2, h3);
            *reinterpret_cast<uint2*>(&hs[p * HS_SLOT + lg * 4]) = W0;
            float g0 = fmaxf(acc1[0] + b1v[1][0], 0.f) * m;
            float g1 = fmaxf(acc1[1] + b1v[1][1], 0.f) * m;
            float g2 = fmaxf(acc1[2] + b1v[1][2], 0.f) * m;
            float g3 = fmaxf(acc1[3] + b1v[1][3], 0.f) * m;
            uint2 W1; W1.x = pk(g0, g1); W1.y = pk(g2, g3);
            *reinterpret_cast<uint2*>(&hs[p * HS_SLOT + 16 + lg * 4]) = W1;
        }
    }
    __syncthreads();

    // ---- P4: conv2 MFMA + epilogue ----
    const int hlane = n * HS_SLOT + lg * 8;
#pragma unroll
    for (int j = 0; j < 4; ++j) {
        int oy = wave + 4 * j;
        f32x4 acc = {0.f,0.f,0.f,0.f};
#pragma unroll
        for (int ks = 0; ks < 9; ++ks) {
            const int dy = ks / 3, dx = ks - 3 * (ks / 3);
            bf16x8 hf = *reinterpret_cast<const bf16x8*>(
                &hs[((oy + dy) * 18 + dx) * HS_SLOT + hlane]);
            acc = __builtin_amdgcn_mfma_f32_16x16x32_bf16(a2[ks], hf, acc, 0, 0, 0);
        }
        float xv = xs[(oy + 4) * 24 + n + 4];
#pragma unroll
        for (int r = 0; r < 4; ++r) {
            float o = fmaxf(acc[r] + b2v[r], 0.f) + wrv[r] * xv + brv[r];
            __builtin_nontemporal_store(
                o, &out[(((size_t)b * 16 + lg * 4 + r) * 512 + (by + oy)) * 512 + (bx + n)]);
        }
    }
}

extern "C" void kernel_launch(void* const* d_in, const int* in_sizes, int n_in,
                              void* d_out, int out_size, void* d_ws, size_t ws_size,
                              hipStream_t stream) {
    const float* x  = (const float*)d_in[0];
    const float* w1 = (const float*)d_in[1];
    const float* b1 = (const float*)d_in[2];
    const float* w2 = (const float*)d_in[3];
    const float* b2 = (const float*)d_in[4];
    const float* wr = (const float*)d_in[5];
    const float* br = (const float*)d_in[6];
    float* out = (float*)d_out;
    short* ws = (short*)d_ws;

    dim3 grid(32, 32, 8);
    dim3 block(256);
    if (ws_size >= WS_BYTES) {
        hipLaunchKernelGGL(setup_frags, dim3(1), dim3(64), 0, stream,
                           w1, b1, w2, b2, wr, br, ws);
        hipLaunchKernelGGL(fused_edge_mfma<true>, grid, block, 0, stream,
                           x, w1, b1, w2, b2, wr, br, ws, out);
    } else {
        hipLaunchKernelGGL(fused_edge_mfma<false>, grid, block, 0, stream,
                           x, w1, b1, w2, b2, wr, br, ws, out);
    }
}

// Round 5
// 95.696 us; speedup vs baseline: 8.0454x; 1.2745x over previous
//
#include <hip/hip_runtime.h>
#include <hip/hip_bf16.h>

// EnhancedEdgeLayer, all-MFMA version (gfx950 mfma_f32_16x16x32_bf16).
// x [8,1,512,512] f32 -> out [8,16,512,512] f32
// Block = 16x16 output tile, 256 threads (4 waves), grid 32x32x8.
//
// R5 changes vs R4:
//  - stencil phase is now MFMA too: edge bank = constant A (M=16, rows 0..8 used,
//    K=32 covering 25 taps), B = per-px 5x5 window gathered from bf16 xs.
//    Replaces ~60 VALU FMA + 27 f2bf per px with 8 ds_read_u16 + 1 MFMA per 16 px.
//  - LDS layouts [half][px][8] (16B per fragment): all ds ops are aligned
//    b128/b64 and contiguous across lanes -> conflict-free.
//    fs2[2][400][8] (12.8KB), hs4[4][324][8] (20.7KB), xs bf16 24x26 (1.2KB).
//  - __float22bfloat162_rn packing, hoisted output addressing, NT stores kept.

typedef __attribute__((ext_vector_type(8))) short bf16x8;
typedef __attribute__((ext_vector_type(4))) float f32x4;

#define XS_S 26   // shorts per xs row

// ws layout (shorts): A1 [2][5][64][8] @0 ; A2 [9][64][8] @5120 ; SB [64][8] @9728
// floats at float-offset 5120: per-lane 20 floats (b1v[2][4], b2v, wrv, brv)
#define WS_A2 5120
#define WS_SB 9728
#define WS_FLT 5120
#define WS_BYTES 25600

__device__ const float EB[9][5][5] = {
 {{0,0,0,0,0},{0,-1,0,1,0},{0,-2,0,2,0},{0,-1,0,1,0},{0,0,0,0,0}},        // sobel_x
 {{0,0,0,0,0},{0,-1,-2,-1,0},{0,0,0,0,0},{0,1,2,1,0},{0,0,0,0,0}},        // sobel_y
 {{0,0,0,0,0},{0,0,1,2,0},{0,-1,0,1,0},{0,-2,-1,0,0},{0,0,0,0,0}},        // diag1
 {{0,0,0,0,0},{0,-2,-1,0,0},{0,-1,0,1,0},{0,0,1,2,0},{0,0,0,0,0}},        // diag2
 {{0,0,0,0,0},{0,0,1,0,0},{0,1,-4,1,0},{0,0,1,0,0},{0,0,0,0,0}},          // laplacian
 {{-1,-2,0,2,1},{-2,-3,0,3,2},{-3,-4,0,4,3},{-2,-3,0,3,2},{-1,-2,0,2,1}}, // gradient5x5
 {{0,0,0,0,0},{0,-3,0,3,0},{0,-10,0,10,0},{0,-3,0,3,0},{0,0,0,0,0}},      // scharr_x
 {{0,0,0,0,0},{0,-3,-10,-3,0},{0,0,0,0,0},{0,3,10,3,0},{0,0,0,0,0}},      // scharr_y
 {{0,0,0,0,0},{0,0,0,0,0},{0,0,1,0,0},{0,0,0,0,0},{0,0,0,0,0}},           // identity
};

__device__ __forceinline__ unsigned short f2bf(float f) {
    union { float f; unsigned u; } v; v.f = f;
    unsigned u = v.u + 0x7fffu + ((v.u >> 16) & 1u);   // RNE
    return (unsigned short)(u >> 16);
}

__global__ __launch_bounds__(64) void setup_frags(
    const float* __restrict__ w1, const float* __restrict__ b1,
    const float* __restrict__ w2, const float* __restrict__ b2,
    const float* __restrict__ wr, const float* __restrict__ br,
    short* __restrict__ ws)
{
    const int lane = threadIdx.x;
    const int n = lane & 15, lg = lane >> 4;
    for (int mt = 0; mt < 2; ++mt)
        for (int ks = 0; ks < 5; ++ks)
            for (int i = 0; i < 8; ++i) {
                int k = 32 * ks + 8 * lg + i;
                int g = k >> 4, ch = k & 15;
                float w = (g < 9 && ch < 9) ? w1[(mt * 16 + n) * 81 + ch * 9 + g] : 0.f;
                ws[((mt * 5 + ks) * 64 + lane) * 8 + i] = (short)f2bf(w);
            }
    for (int ks = 0; ks < 9; ++ks)
        for (int i = 0; i < 8; ++i) {
            int ic = 8 * lg + i;
            ws[WS_A2 + (ks * 64 + lane) * 8 + i] = (short)f2bf(w2[n * 288 + ic * 9 + ks]);
        }
    for (int i = 0; i < 8; ++i) {
        int k = 8 * lg + i;
        float v = (k < 25 && n < 9) ? EB[n][k / 5][k % 5] : 0.f;
        ws[WS_SB + lane * 8 + i] = (short)f2bf(v);
    }
    float* wf = (float*)ws + WS_FLT + lane * 20;
    for (int r = 0; r < 4; ++r) {
        wf[r]      = b1[lg * 4 + r];
        wf[4 + r]  = b1[16 + lg * 4 + r];
        wf[8 + r]  = b2[lg * 4 + r];
        wf[12 + r] = wr[lg * 4 + r];
        wf[16 + r] = br[lg * 4 + r];
    }
}

template<bool USE_WS>
__global__ __launch_bounds__(256, 4) void fused_edge_mfma(
    const float* __restrict__ x,  const float* __restrict__ w1, const float* __restrict__ b1,
    const float* __restrict__ w2, const float* __restrict__ b2,
    const float* __restrict__ wr, const float* __restrict__ br,
    const short* __restrict__ ws, float* __restrict__ out)
{
    __shared__ short fs2[2 * 400 * 8];   // 12800 B  [ch-half][px 20x20][8]
    __shared__ short hs4[4 * 324 * 8];   // 20736 B  [ic-block][px 18x18][8]
    __shared__ short xs[24 * XS_S];      //  1248 B  bf16 x tile

    const int tid  = threadIdx.x;
    const int lane = tid & 63;
    const int wave = tid >> 6;
    const int n    = lane & 15;
    const int lg   = lane >> 4;
    const int bx = blockIdx.x * 16, by = blockIdx.y * 16, b = blockIdx.z;

    // ---- P0: x tile -> bf16 LDS (zero-padded) ----
    for (int i = tid; i < 576; i += 256) {
        int r = i / 24, c = i % 24;
        int gy = by - 4 + r, gx = bx - 4 + c;
        float v = 0.f;
        if (gy >= 0 && gy < 512 && gx >= 0 && gx < 512) v = x[(b * 512 + gy) * 512 + gx];
        __hip_bfloat16 h = __float2bfloat16(v);
        xs[r * XS_S + c] = *reinterpret_cast<short*>(&h);
    }

    // ---- P1: weight fragments -> registers ----
    bf16x8 a1[2][5], a2[9], sb;
    float b1v[2][4], b2v[4], wrv[4], brv[4];
    if (USE_WS) {
#pragma unroll
        for (int mt = 0; mt < 2; ++mt)
#pragma unroll
            for (int ks = 0; ks < 5; ++ks)
                a1[mt][ks] = *reinterpret_cast<const bf16x8*>(&ws[((mt * 5 + ks) * 64 + lane) * 8]);
#pragma unroll
        for (int ks = 0; ks < 9; ++ks)
            a2[ks] = *reinterpret_cast<const bf16x8*>(&ws[WS_A2 + (ks * 64 + lane) * 8]);
        sb = *reinterpret_cast<const bf16x8*>(&ws[WS_SB + lane * 8]);
        const float* wf = (const float*)ws + WS_FLT + lane * 20;
        f32x4 t0 = *reinterpret_cast<const f32x4*>(wf);
        f32x4 t1 = *reinterpret_cast<const f32x4*>(wf + 4);
        f32x4 t2 = *reinterpret_cast<const f32x4*>(wf + 8);
        f32x4 t3 = *reinterpret_cast<const f32x4*>(wf + 12);
        f32x4 t4 = *reinterpret_cast<const f32x4*>(wf + 16);
#pragma unroll
        for (int r = 0; r < 4; ++r) {
            b1v[0][r] = t0[r]; b1v[1][r] = t1[r];
            b2v[r] = t2[r]; wrv[r] = t3[r]; brv[r] = t4[r];
        }
    } else {
#pragma unroll
        for (int mt = 0; mt < 2; ++mt)
#pragma unroll
            for (int ks = 0; ks < 5; ++ks)
#pragma unroll
                for (int i = 0; i < 8; ++i) {
                    int k = 32 * ks + 8 * lg + i;
                    int g = k >> 4, ch = k & 15;
                    float w = (g < 9 && ch < 9) ? w1[(mt * 16 + n) * 81 + ch * 9 + g] : 0.f;
                    a1[mt][ks][i] = (short)f2bf(w);
                }
#pragma unroll
        for (int ks = 0; ks < 9; ++ks)
#pragma unroll
            for (int i = 0; i < 8; ++i)
                a2[ks][i] = (short)f2bf(w2[n * 288 + (8 * lg + i) * 9 + ks]);
#pragma unroll
        for (int i = 0; i < 8; ++i) {
            int k = 8 * lg + i;
            float v = (k < 25 && n < 9) ? EB[n][k / 5][k % 5] : 0.f;
            sb[i] = (short)f2bf(v);
        }
#pragma unroll
        for (int r = 0; r < 4; ++r) {
            b1v[0][r] = b1[lg * 4 + r]; b1v[1][r] = b1[16 + lg * 4 + r];
            b2v[r] = b2[lg * 4 + r]; wrv[r] = wr[lg * 4 + r]; brv[r] = br[lg * 4 + r];
        }
    }

    // per-lane gather tables
    int toff[8];   // P2: tap offsets into xs
#pragma unroll
    for (int i = 0; i < 8; ++i) {
        int k = 8 * lg + i;
        int t = k < 25 ? k : 24;           // k>=25: A rows are 0, value irrelevant
        toff[i] = (t / 5) * XS_S + (t % 5);
    }
    int boff[5];   // P3: conv1 B offsets into fs2 (shorts)
#pragma unroll
    for (int ks = 0; ks < 5; ++ks) {
        int g = 2 * ks + (lg >> 1); if (g > 8) g = 8;   // g==9 slots have A==0
        int dy = g / 3, dx = g - 3 * dy;
        boff[ks] = (lg & 1) * 3200 + (dy * 20 + dx) * 8;
    }

    __syncthreads();

    // ---- P2: stencils via MFMA -> fs2 [half][px][8] ----
    for (int t = wave; t < 25; t += 4) {
        int px = t * 16 + n;
        int r = px / 20, c = px - 20 * r;
        const short* base = &xs[r * XS_S + c];
        bf16x8 bv;
#pragma unroll
        for (int i = 0; i < 8; ++i) bv[i] = base[toff[i]];
        f32x4 f = {0.f, 0.f, 0.f, 0.f};
        f = __builtin_amdgcn_mfma_f32_16x16x32_bf16(sb, bv, f, 0, 0, 0);
        int fy = by + r - 2, fx = bx + c - 2;
        float m = (fy >= 0 && fy < 512 && fx >= 0 && fx < 512) ? 1.f : 0.f;
        __hip_bfloat162 p0 = __float22bfloat162_rn(make_float2(f[0] * m, f[1] * m));
        __hip_bfloat162 p1 = __float22bfloat162_rn(make_float2(f[2] * m, f[3] * m));
        uint2 wv;
        wv.x = *reinterpret_cast<unsigned*>(&p0);
        wv.y = *reinterpret_cast<unsigned*>(&p1);
        *reinterpret_cast<uint2*>(&fs2[((lg >> 1) * 400 + px) * 8 + 4 * (lg & 1)]) = wv;
    }
    __syncthreads();

    // ---- P3: conv1 MFMA -> hs4 [ic-block][px][8] ----
    for (int t = wave; t < 21; t += 4) {
        int p  = t * 16 + n;
        int pc = p < 323 ? p : 323;
        int r1 = pc / 18, c1 = pc - 18 * r1;
        int base = (r1 * 20 + c1) * 8;
        f32x4 acc0 = {0.f,0.f,0.f,0.f}, acc1 = {0.f,0.f,0.f,0.f};
#pragma unroll
        for (int ks = 0; ks < 5; ++ks) {
            bf16x8 bf = *reinterpret_cast<const bf16x8*>(&fs2[base + boff[ks]]);
            acc0 = __builtin_amdgcn_mfma_f32_16x16x32_bf16(a1[0][ks], bf, acc0, 0, 0, 0);
            acc1 = __builtin_amdgcn_mfma_f32_16x16x32_bf16(a1[1][ks], bf, acc1, 0, 0, 0);
        }
        if (p < 324) {
            int hy = by - 1 + r1, hx = bx - 1 + c1;
            float m = (hy >= 0 && hy < 512 && hx >= 0 && hx < 512) ? 1.f : 0.f;
            __hip_bfloat162 q0 = __float22bfloat162_rn(make_float2(
                fmaxf(acc0[0] + b1v[0][0], 0.f) * m, fmaxf(acc0[1] + b1v[0][1], 0.f) * m));
            __hip_bfloat162 q1 = __float22bfloat162_rn(make_float2(
                fmaxf(acc0[2] + b1v[0][2], 0.f) * m, fmaxf(acc0[3] + b1v[0][3], 0.f) * m));
            uint2 W0; W0.x = *reinterpret_cast<unsigned*>(&q0);
            W0.y = *reinterpret_cast<unsigned*>(&q1);
            *reinterpret_cast<uint2*>(&hs4[((lg >> 1) * 324 + p) * 8 + 4 * (lg & 1)]) = W0;
            __hip_bfloat162 q2 = __float22bfloat162_rn(make_float2(
                fmaxf(acc1[0] + b1v[1][0], 0.f) * m, fmaxf(acc1[1] + b1v[1][1], 0.f) * m));
            __hip_bfloat162 q3 = __float22bfloat162_rn(make_float2(
                fmaxf(acc1[2] + b1v[1][2], 0.f) * m, fmaxf(acc1[3] + b1v[1][3], 0.f) * m));
            uint2 W1; W1.x = *reinterpret_cast<unsigned*>(&q2);
            W1.y = *reinterpret_cast<unsigned*>(&q3);
            *reinterpret_cast<uint2*>(&hs4[((2 + (lg >> 1)) * 324 + p) * 8 + 4 * (lg & 1)]) = W1;
        }
    }
    __syncthreads();

    // ---- P4: conv2 MFMA + epilogue ----
    const int hbase = lg * 324 * 8;
#pragma unroll
    for (int j = 0; j < 4; ++j) {
        int oy = wave + 4 * j;
        f32x4 acc = {0.f,0.f,0.f,0.f};
#pragma unroll
        for (int ks = 0; ks < 9; ++ks) {
            const int dy = ks / 3, dx = ks - 3 * (ks / 3);
            bf16x8 hf = *reinterpret_cast<const bf16x8*>(
                &hs4[hbase + ((oy + dy) * 18 + n + dx) * 8]);
            acc = __builtin_amdgcn_mfma_f32_16x16x32_bf16(a2[ks], hf, acc, 0, 0, 0);
        }
        __hip_bfloat16 xh = *reinterpret_cast<const __hip_bfloat16*>(&xs[(oy + 4) * XS_S + n + 4]);
        float xv = __bfloat162float(xh);
        float* op = out + (((size_t)(b * 16 + lg * 4) * 512 + (by + oy)) * 512) + bx + n;
#pragma unroll
        for (int r = 0; r < 4; ++r) {
            float o = fmaxf(acc[r] + b2v[r], 0.f) + wrv[r] * xv + brv[r];
            __builtin_nontemporal_store(o, op);
            op += 262144;   // next oc plane
        }
    }
}

extern "C" void kernel_launch(void* const* d_in, const int* in_sizes, int n_in,
                              void* d_out, int out_size, void* d_ws, size_t ws_size,
                              hipStream_t stream) {
    const float* x  = (const float*)d_in[0];
    const float* w1 = (const float*)d_in[1];
    const float* b1 = (const float*)d_in[2];
    const float* w2 = (const float*)d_in[3];
    const float* b2 = (const float*)d_in[4];
    const float* wr = (const float*)d_in[5];
    const float* br = (const float*)d_in[6];
    float* out = (float*)d_out;
    short* ws = (short*)d_ws;

    dim3 grid(32, 32, 8);
    dim3 block(256);
    if (ws_size >= WS_BYTES) {
        hipLaunchKernelGGL(setup_frags, dim3(1), dim3(64), 0, stream,
                           w1, b1, w2, b2, wr, br, ws);
        hipLaunchKernelGGL(fused_edge_mfma<true>, grid, block, 0, stream,
                           x, w1, b1, w2, b2, wr, br, ws, out);
    } else {
        hipLaunchKernelGGL(fused_edge_mfma<false>, grid, block, 0, stream,
                           x, w1, b1, w2, b2, wr, br, ws, out);
    }
}